// Round 9
// baseline (129.705 us; speedup 1.0000x reference)
//
#include <hip/hip_runtime.h>

#define LENY  1048576
#define NU    (LENY - 1)      // length of u_combined
#define NRBF  11
#define NB    2048            // 8 blocks/CU -> exact-fit co-resident (R7-verified)
#define NT    256             // 4 waves per block
#define NW    (NT / 64)
#define PERT  2               // consecutive elements per thread
#define CHUNK (NT * PERT)     // 512; NB*CHUNK == LENY
#define SPT   (NB / NT)       // sweeper: bsums entries per thread = 8

typedef float v4f __attribute__((ext_vector_type(4)));

#define L2E 1.44269504088896340736f   // log2(e)

__device__ __forceinline__ float fexp(float x) {
    return __builtin_amdgcn_exp2f(x * L2E);
}
__device__ __forceinline__ float sigmoid10(float x) {
    x = fminf(10.0f, fmaxf(-10.0f, x));
    const float e = __builtin_amdgcn_exp2f(-x * L2E);
    return __builtin_amdgcn_rcpf(1.0f + e);
}

// Relaxed agent-scope atomics: reach the coherence point (L3), emit NO
// buffer_inv/buffer_wbl2 cache maintenance (acq/rel poisoned R2: 62us).
__device__ __forceinline__ void st_relaxed_u64(unsigned long long* p, unsigned long long v) {
    __hip_atomic_store(p, v, __ATOMIC_RELAXED, __HIP_MEMORY_SCOPE_AGENT);
}
__device__ __forceinline__ unsigned long long ld_relaxed_u64(const unsigned long long* p) {
    return __hip_atomic_load(p, __ATOMIC_RELAXED, __HIP_MEMORY_SCOPE_AGENT);
}
__device__ __forceinline__ void st_relaxed_u32(unsigned* p, unsigned v) {
    __hip_atomic_store(p, v, __ATOMIC_RELAXED, __HIP_MEMORY_SCOPE_AGENT);
}
__device__ __forceinline__ unsigned ld_relaxed_u32(const unsigned* p) {
    return __hip_atomic_load(p, __ATOMIC_RELAXED, __HIP_MEMORY_SCOPE_AGENT);
}
__device__ __forceinline__ unsigned fadd_relaxed_u32(unsigned* p, unsigned v) {
    return __hip_atomic_fetch_add(p, v, __ATOMIC_RELAXED, __HIP_MEMORY_SCOPE_AGENT);
}
__device__ __forceinline__ double bitsd(unsigned long long v) {
    return __builtin_bit_cast(double, v);
}
__device__ __forceinline__ unsigned long long dbits(double v) {
    return __builtin_bit_cast(unsigned long long, v);
}

// One-pass fused scan with elected-sweeper barrier:
//   every block publishes its aggregate + arrives on a counter; the LAST
//   arriver (all aggregates now at L3) scans all 2048 aggregates alone,
//   publishes per-block exclusive offsets, raises one go flag. O(1) sync
//   state per block — no O(b) lookback, no inclusive-prefix chains.
__global__ __launch_bounds__(NT, 8) void rbf_onepass(
    const float2* __restrict__ yin,
    const float2* __restrict__ xa,
    const float2* __restrict__ xb,
    const float*  __restrict__ rbfw_raw,
    const float*  __restrict__ weights,
    const float*  __restrict__ g1raw,
    const float*  __restrict__ g2raw,
    float2* __restrict__ yout,
    float2* __restrict__ uout,
    double2* __restrict__ bsums,
    double2* __restrict__ offs,
    unsigned* __restrict__ sync)   // sync[0]=arrive counter, sync[1]=go
{
    const int b = blockIdx.x, t = threadIdx.x;
    const int lane = t & 63, wid = t >> 6;
    const int base = b * CHUNK + t * PERT;

    // ---- uniform params ----
    const float RBFw    = sigmoid10(rbfw_raw[0]);
    const float wdt     = RBFw * 0.2f;
    const float negInvL = -L2E / (2.0f * wdt * wdt);
    const float g1 = fexp(g1raw[0]);
    const float g2 = fexp(g2raw[0]);
    const float Bf = (float)(1.0 / 60.0);
    const float2 y0 = yin[0];

    float wj[NRBF];
    #pragma unroll
    for (int j = 0; j < NRBF; ++j) wj[j] = weights[j];

    // ---- 16B/lane nontemporal input loads ----
    const v4f yv = __builtin_nontemporal_load((const v4f*)yin + (base >> 1));
    const v4f av = __builtin_nontemporal_load((const v4f*)xa  + (base >> 1));
    const v4f bv = __builtin_nontemporal_load((const v4f*)xb  + (base >> 1));

    // ---- compute u in registers, per-thread double sums ----
    float ux[PERT], uy[PERT];
    double sx = 0.0, sy = 0.0;
    #pragma unroll
    for (int k = 0; k < PERT; ++k) {
        const int gi = base + k;
        const float ti = ((float)gi - 524287.5f) / 524287.5f;
        float dot = 0.0f;
        #pragma unroll
        for (int j = 0; j < NRBF; ++j) {
            const float c = -1.0f + 0.2f * (float)j;
            const float d = ti - c;
            dot += __builtin_amdgcn_exp2f(d * d * negInvL) * wj[j];
        }
        const float wt = sigmoid10(dot);
        const float eyx = yv[2*k], eyy = yv[2*k+1];
        const float eax = av[2*k], eay = av[2*k+1];
        const float ebx = bv[2*k], eby = bv[2*k+1];
        const float u1x = -g1 * (eyx - eax);
        const float u1y = -g1 * (eyy - eay);
        const float u2x = -g2 * (eyx - ebx);
        const float u2y = -g2 * (eyy - eby);
        ux[k] = u1x * (1.0f - wt) + u2x * wt;
        uy[k] = u1y * (1.0f - wt) + u2y * wt;
        sx += (double)(ux[k] * Bf);   // phantom elem LENY-1: its contribution
        sy += (double)(uy[k] * Bf);   // never reaches any STORED prefix
    }

    // ---- block scan: wave shfl_up + wave totals (1 barrier) ----
    double ix = sx, iy = sy;
    #pragma unroll
    for (int d = 1; d < 64; d <<= 1) {
        const double px = __shfl_up(ix, d, 64);
        const double py = __shfl_up(iy, d, 64);
        if (lane >= d) { ix += px; iy += py; }
    }
    __shared__ double2 wtot[NW];
    if (lane == 63) wtot[wid] = make_double2(ix, iy);
    __syncthreads();
    double wbx = 0.0, wby = 0.0, totx = 0.0, toty = 0.0;
    #pragma unroll
    for (int w = 0; w < NW; ++w) {
        const double vx = wtot[w].x, vy = wtot[w].y;
        totx += vx; toty += vy;
        if (w < wid) { wbx += vx; wby += vy; }
    }
    const double myex = wbx + ix - sx;   // exclusive in-block prefix
    const double myey = wby + iy - sy;

    // ---- publish aggregate + arrive (payload -> vmcnt(0) -> fetch_add) ----
    __shared__ int is_sweeper;
    if (t == 0) {
        st_relaxed_u64((unsigned long long*)&bsums[b].x, dbits(totx));
        st_relaxed_u64((unsigned long long*)&bsums[b].y, dbits(toty));
        asm volatile("s_waitcnt vmcnt(0)" ::: "memory");
        const unsigned old = fadd_relaxed_u32(&sync[0], 1u);
        is_sweeper = (old == NB - 1u);
    }

    // ---- store u while others arrive (overlaps sync latency) ----
    if (base + PERT <= NU) {
        v4f r = { ux[0], uy[0], ux[1], uy[1] };
        __builtin_nontemporal_store(r, (v4f*)uout + (base >> 1));
    } else {
        for (int k = 0; k < PERT; ++k)
            if (base + k < NU) uout[base + k] = make_float2(ux[k], uy[k]);
    }

    __syncthreads();                       // broadcast is_sweeper
    if (is_sweeper) {
        // All 2048 aggregates are at L3 (every arriver drained before add).
        asm volatile("" ::: "memory");
        double bxv[SPT], byv[SPT];
        const int rbase = t * SPT;
        #pragma unroll
        for (int i = 0; i < SPT; ++i) {    // 16 independent uncached loads
            bxv[i] = bitsd(ld_relaxed_u64((const unsigned long long*)&bsums[rbase + i].x));
            byv[i] = bitsd(ld_relaxed_u64((const unsigned long long*)&bsums[rbase + i].y));
        }
        double rx = 0.0, ry = 0.0;         // run total + exclusive-within-run
        double pxr[SPT], pyr[SPT];
        #pragma unroll
        for (int i = 0; i < SPT; ++i) {
            pxr[i] = rx; pyr[i] = ry;
            rx += bxv[i]; ry += byv[i];
        }
        // wave inclusive scan of run totals
        double sxw = rx, syw = ry;
        #pragma unroll
        for (int d = 1; d < 64; d <<= 1) {
            const double px = __shfl_up(sxw, d, 64);
            const double py = __shfl_up(syw, d, 64);
            if (lane >= d) { sxw += px; syw += py; }
        }
        __shared__ double2 swt[NW];
        if (lane == 63) swt[wid] = make_double2(sxw, syw);
        __syncthreads();
        double cbx = 0.0, cby = 0.0;
        #pragma unroll
        for (int w = 0; w < NW; ++w)
            if (w < wid) { cbx += swt[w].x; cby += swt[w].y; }
        const double ebx = cbx + sxw - rx;  // exclusive prefix of this run
        const double eby = cby + syw - ry;
        #pragma unroll
        for (int i = 0; i < SPT; ++i) {
            st_relaxed_u64((unsigned long long*)&offs[rbase + i].x, dbits(ebx + pxr[i]));
            st_relaxed_u64((unsigned long long*)&offs[rbase + i].y, dbits(eby + pyr[i]));
        }
        asm volatile("s_waitcnt vmcnt(0)" ::: "memory");  // offs at L3
        __syncthreads();                   // all sweeper waves drained
        if (t == 0) st_relaxed_u32(&sync[1], 1u);
    } else {
        if (t == 0) {
            while (ld_relaxed_u32(&sync[1]) == 0u) __builtin_amdgcn_s_sleep(4);
        }
    }
    __syncthreads();
    asm volatile("" ::: "memory");

    // ---- one 16B offset read per thread (same addr -> L3 line reuse) ----
    const double offx = bitsd(ld_relaxed_u64((const unsigned long long*)&offs[b].x));
    const double offy = bitsd(ld_relaxed_u64((const unsigned long long*)&offs[b].y));

    // ---- exclusive-scan y write (16B nt stores; y[0]=yin[0] falls out) ----
    double runx = offx + myex, runy = offy + myey;
    const double y0x = (double)y0.x, y0y = (double)y0.y;

    const float o0x = (float)(y0x + runx);
    const float o0y = (float)(y0y + runy);
    runx += (double)(ux[0] * Bf);
    runy += (double)(uy[0] * Bf);
    const float o1x = (float)(y0x + runx);
    const float o1y = (float)(y0y + runy);
    v4f r = { o0x, o0y, o1x, o1y };
    __builtin_nontemporal_store(r, (v4f*)yout + (base >> 1));
}

extern "C" void kernel_launch(void* const* d_in, const int* in_sizes, int n_in,
                              void* d_out, int out_size, void* d_ws, size_t ws_size,
                              hipStream_t stream) {
    const float2* yin  = (const float2*)d_in[0];
    const float2* xa   = (const float2*)d_in[1];
    const float2* xb   = (const float2*)d_in[2];
    const float*  rbfw = (const float*)d_in[3];
    const float*  wts  = (const float*)d_in[4];
    const float*  g1   = (const float*)d_in[5];
    const float*  g2   = (const float*)d_in[6];

    float*  out  = (float*)d_out;
    float2* yout = (float2*)out;                 // y: LENY x 2
    float2* uout = (float2*)(out + 2 * LENY);    // u_combined: (LENY-1) x 2

    double2*  bsums = (double2*)d_ws;                               // 32 KB
    double2*  offs  = (double2*)((char*)d_ws + 32768);              // 32 KB
    unsigned* syncw = (unsigned*)((char*)d_ws + 65536);             //  8 B

    // counter+go must be 0 at kernel start on every replay.
    hipMemsetAsync(syncw, 0, 2 * sizeof(unsigned), stream);

    rbf_onepass<<<NB, NT, 0, stream>>>(yin, xa, xb, rbfw, wts, g1, g2,
                                       yout, uout, bsums, offs, syncw);
}

// Round 10
// 19.203 us; speedup vs baseline: 6.7546x; 6.7546x over previous
//
#include <hip/hip_runtime.h>

#define LENY  1048576
#define NU    (LENY - 1)      // length of u_combined
#define NRBF  11
#define NB    2048            // 8 blocks/CU -> 32 waves/CU full occupancy
#define NT    256             // 4 waves per block
#define NW    (NT / 64)
#define PERT  2               // consecutive elements per thread
#define CHUNK (NT * PERT)     // 512; NB*CHUNK == LENY

typedef float v4f __attribute__((ext_vector_type(4)));

#define L2E 1.44269504088896340736f   // log2(e)

__device__ __forceinline__ float fexp(float x) {
    return __builtin_amdgcn_exp2f(x * L2E);
}
__device__ __forceinline__ float sigmoid10(float x) {
    x = fminf(10.0f, fmaxf(-10.0f, x));
    const float e = __builtin_amdgcn_exp2f(-x * L2E);
    return __builtin_amdgcn_rcpf(1.0f + e);
}

// Shared u-compute: MUST be bit-identical in both kernels (recompute scheme).
// Returns per-thread (sum_x, sum_y) of B'*u over its PERT elements; fills ux/uy.
__device__ __forceinline__ void compute_u(
    int base, const v4f yv, const v4f av, const v4f bv,
    float negInvL, float g1, float g2, const float* wj,
    float* ux, float* uy, double& sx, double& sy)
{
    const float Bf = (float)(1.0 / 60.0);
    sx = 0.0; sy = 0.0;
    #pragma unroll
    for (int k = 0; k < PERT; ++k) {
        const int gi = base + k;
        const float ti = ((float)gi - 524287.5f) / 524287.5f;
        float dot = 0.0f;
        #pragma unroll
        for (int j = 0; j < NRBF; ++j) {
            const float c = -1.0f + 0.2f * (float)j;   // linspace(-1,1,11)
            const float d = ti - c;
            dot += __builtin_amdgcn_exp2f(d * d * negInvL) * wj[j];
        }
        const float wt = sigmoid10(dot);
        const float eyx = yv[2*k], eyy = yv[2*k+1];
        const float eax = av[2*k], eay = av[2*k+1];
        const float ebx = bv[2*k], eby = bv[2*k+1];
        const float u1x = -g1 * (eyx - eax);
        const float u1y = -g1 * (eyy - eay);
        const float u2x = -g2 * (eyx - ebx);
        const float u2y = -g2 * (eyy - eby);
        ux[k] = u1x * (1.0f - wt) + u2x * wt;
        uy[k] = u1y * (1.0f - wt) + u2y * wt;
        sx += (double)(ux[k] * Bf);   // phantom elem LENY-1: exclusive scan means
        sy += (double)(uy[k] * Bf);   // it never reaches any stored prefix
    }
}

// ---- k1: read inputs (cached -> warm L3 for k2), emit ONLY block sums ------
__global__ __launch_bounds__(NT) void rbf_sum(
    const float2* __restrict__ yin,
    const float2* __restrict__ xa,
    const float2* __restrict__ xb,
    const float*  __restrict__ rbfw_raw,
    const float*  __restrict__ weights,
    const float*  __restrict__ g1raw,
    const float*  __restrict__ g2raw,
    double2* __restrict__ bsums)
{
    const int b = blockIdx.x, t = threadIdx.x;
    const int lane = t & 63, wid = t >> 6;
    const int base = b * CHUNK + t * PERT;

    const float RBFw    = sigmoid10(rbfw_raw[0]);
    const float wdt     = RBFw * 0.2f;
    const float negInvL = -L2E / (2.0f * wdt * wdt);
    const float g1 = fexp(g1raw[0]);
    const float g2 = fexp(g2raw[0]);

    float wj[NRBF];
    #pragma unroll
    for (int j = 0; j < NRBF; ++j) wj[j] = weights[j];

    // cached loads on purpose: leave inputs resident in L2/L3 for k2
    const v4f yv = *((const v4f*)yin + (base >> 1));
    const v4f av = *((const v4f*)xa  + (base >> 1));
    const v4f bv = *((const v4f*)xb  + (base >> 1));

    float ux[PERT], uy[PERT];
    double sx, sy;
    compute_u(base, yv, av, bv, negInvL, g1, g2, wj, ux, uy, sx, sy);

    #pragma unroll
    for (int d = 32; d > 0; d >>= 1) {
        sx += __shfl_down(sx, d);
        sy += __shfl_down(sy, d);
    }
    __shared__ double2 wtot[NW];
    if (lane == 0) wtot[wid] = make_double2(sx, sy);
    __syncthreads();
    if (t == 0) {
        double tx = 0.0, ty = 0.0;
        #pragma unroll
        for (int w = 0; w < NW; ++w) { tx += wtot[w].x; ty += wtot[w].y; }
        bsums[b] = make_double2(tx, ty);
    }
}

// ---- k2: re-read inputs (L3-hot), recompute u, write u AND y --------------
__global__ __launch_bounds__(NT) void rbf_out(
    const float2* __restrict__ yin,
    const float2* __restrict__ xa,
    const float2* __restrict__ xb,
    const float*  __restrict__ rbfw_raw,
    const float*  __restrict__ weights,
    const float*  __restrict__ g1raw,
    const float*  __restrict__ g2raw,
    const double2* __restrict__ bsums,
    float2* __restrict__ uout,
    float2* __restrict__ yout)
{
    const int b = blockIdx.x, t = threadIdx.x;
    const int lane = t & 63, wid = t >> 6;
    const int base = b * CHUNK + t * PERT;
    const float Bf = (float)(1.0 / 60.0);

    const float RBFw    = sigmoid10(rbfw_raw[0]);
    const float wdt     = RBFw * 0.2f;
    const float negInvL = -L2E / (2.0f * wdt * wdt);
    const float g1 = fexp(g1raw[0]);
    const float g2 = fexp(g2raw[0]);
    const float2 y0 = yin[0];

    float wj[NRBF];
    #pragma unroll
    for (int j = 0; j < NRBF; ++j) wj[j] = weights[j];

    // issue input loads (L3-hot), then overlap the bsums offset loop
    const v4f yv = *((const v4f*)yin + (base >> 1));
    const v4f av = *((const v4f*)xa  + (base >> 1));
    const v4f bv = *((const v4f*)xb  + (base >> 1));

    // block offset partials: <=8 cached 16B loads per thread
    double ox = 0.0, oy = 0.0;
    for (int j = t; j < b; j += NT) { ox += bsums[j].x; oy += bsums[j].y; }
    #pragma unroll
    for (int d = 32; d > 0; d >>= 1) {
        ox += __shfl_down(ox, d);
        oy += __shfl_down(oy, d);
    }

    // recompute u (bit-identical to k1)
    float ux[PERT], uy[PERT];
    double sx, sy;
    compute_u(base, yv, av, bv, negInvL, g1, g2, wj, ux, uy, sx, sy);

    // wave inclusive scan of per-thread sums
    double ix = sx, iy = sy;
    #pragma unroll
    for (int d = 1; d < 64; d <<= 1) {
        const double px = __shfl_up(ix, d, 64);
        const double py = __shfl_up(iy, d, 64);
        if (lane >= d) { ix += px; iy += py; }
    }

    // single barrier: offset partials + scan wave totals in separate arrays
    __shared__ double2 wred[NW];   // per-wave offset partial sums
    __shared__ double2 wtot[NW];   // per-wave scan totals
    if (lane == 0)  wred[wid] = make_double2(ox, oy);
    if (lane == 63) wtot[wid] = make_double2(ix, iy);
    __syncthreads();

    double offx = 0.0, offy = 0.0, wbx = 0.0, wby = 0.0;
    #pragma unroll
    for (int w = 0; w < NW; ++w) {
        offx += wred[w].x; offy += wred[w].y;
        if (w < wid) { wbx += wtot[w].x; wby += wtot[w].y; }
    }
    const double myex = wbx + ix - sx;   // exclusive in-block prefix
    const double myey = wby + iy - sy;

    // ---- store u (nt; element NU does not exist) ----
    if (base + PERT <= NU) {
        v4f r = { ux[0], uy[0], ux[1], uy[1] };
        __builtin_nontemporal_store(r, (v4f*)uout + (base >> 1));
    } else {
        for (int k = 0; k < PERT; ++k)
            if (base + k < NU) uout[base + k] = make_float2(ux[k], uy[k]);
    }

    // ---- exclusive-scan y write (16B nt; y[0]=yin[0] falls out) ----
    double runx = offx + myex, runy = offy + myey;
    const double y0x = (double)y0.x, y0y = (double)y0.y;

    const float o0x = (float)(y0x + runx);
    const float o0y = (float)(y0y + runy);
    runx += (double)(ux[0] * Bf);
    runy += (double)(uy[0] * Bf);
    const float o1x = (float)(y0x + runx);
    const float o1y = (float)(y0y + runy);
    v4f r = { o0x, o0y, o1x, o1y };
    __builtin_nontemporal_store(r, (v4f*)yout + (base >> 1));
}

extern "C" void kernel_launch(void* const* d_in, const int* in_sizes, int n_in,
                              void* d_out, int out_size, void* d_ws, size_t ws_size,
                              hipStream_t stream) {
    const float2* yin  = (const float2*)d_in[0];
    const float2* xa   = (const float2*)d_in[1];
    const float2* xb   = (const float2*)d_in[2];
    const float*  rbfw = (const float*)d_in[3];
    const float*  wts  = (const float*)d_in[4];
    const float*  g1   = (const float*)d_in[5];
    const float*  g2   = (const float*)d_in[6];

    float*  out  = (float*)d_out;
    float2* yout = (float2*)out;                 // y: LENY x 2
    float2* uout = (float2*)(out + 2 * LENY);    // u_combined: (LENY-1) x 2
    double2* bsums = (double2*)d_ws;             // 2048 * 16 B = 32 KB

    rbf_sum<<<NB, NT, 0, stream>>>(yin, xa, xb, rbfw, wts, g1, g2, bsums);
    rbf_out<<<NB, NT, 0, stream>>>(yin, xa, xb, rbfw, wts, g1, g2,
                                   bsums, uout, yout);
}